// Round 6
// baseline (148.949 us; speedup 1.0000x reference)
//
#include <hip/hip_runtime.h>
#include <math.h>

#define NB 4
#define LQ 2048
#define DM 256
#define HH 6
#define DH 64
#define LIN 16464
#define LINP 16512          // padded rows per batch (129 * 128)
#define NOA 512             // fused off(324)+attn(162) padded
#define NVAL 384

typedef unsigned short ushort_t;
typedef unsigned int uint_t;
typedef __attribute__((ext_vector_type(8))) short s8v;   // 8 bf16 = 4 VGPR
typedef __attribute__((ext_vector_type(4))) float f4v;   // MFMA accumulator

__device__ __forceinline__ ushort_t f2bf(float f) {
  union { float f; unsigned u; } v; v.f = f;
  unsigned r = v.u + 0x7fffu + ((v.u >> 16) & 1u);  // RNE
  return (ushort_t)(r >> 16);
}

typedef __attribute__((address_space(3))) char lds_char_t;
typedef const __attribute__((address_space(1))) char glb_char_t;
__device__ __forceinline__ void gload16(const void* g, void* l) {
  __builtin_amdgcn_global_load_lds((glb_char_t*)g, (lds_char_t*)l, 16, 0, 0);
}

// ---------------- q = bf16(tgt + query_pos) ----------------
__global__ __launch_bounds__(256)
void addq_k(const float4* __restrict__ a, const float4* __restrict__ b,
            ushort4* __restrict__ o, int n) {
  int i = blockIdx.x * 256 + threadIdx.x;
  if (i < n) {
    float4 x = a[i], y = b[i];
    ushort4 r;
    r.x = f2bf(x.x + y.x); r.y = f2bf(x.y + y.y);
    r.z = f2bf(x.z + y.z); r.w = f2bf(x.w + y.w);
    o[i] = r;
  }
}

// ---------------- src fp32 -> bf16, padded to LINP rows per batch ----------------
__global__ __launch_bounds__(256)
void conv_pad_k(const float4* __restrict__ src, ushort4* __restrict__ dst) {
  const int idx = blockIdx.x * 256 + threadIdx.x;   // over LINP*64 quads
  const int b = blockIdx.y;
  const int r = idx >> 6, kq = idx & 63;
  ushort4 o;
  if (r < LIN) {
    float4 x = src[(size_t)(b * LIN + r) * 64 + kq];
    o.x = f2bf(x.x); o.y = f2bf(x.y); o.z = f2bf(x.z); o.w = f2bf(x.w);
  } else {
    o.x = o.y = o.z = o.w = 0;
  }
  dst[(size_t)(b * LINP + r) * 64 + kq] = o;
}

// ------------- generic weight transpose: Bt[n][k] = bf16(B[k][n]), 0 if n>=N -------------
__global__ __launch_bounds__(256)
void tconv_k(const float* __restrict__ B, ushort_t* __restrict__ Bt,
             int K, int N, int total) {
  int i = blockIdx.x * 256 + threadIdx.x;
  if (i >= total) return;
  int n = i / K, k = i - n * K;
  Bt[i] = (n < N) ? f2bf(B[(size_t)k * N + n]) : (ushort_t)0;
}

// ------------- fused off+attn weight: rows 0..323 W_off, 324..485 W_attn, rest 0 -------------
__global__ __launch_bounds__(256)
void tconv_oa_k(const float* __restrict__ Woff, const float* __restrict__ Wattn,
                ushort_t* __restrict__ Bt) {
  int i = blockIdx.x * 256 + threadIdx.x;   // 512*256
  int n = i >> 8, k = i & 255;
  float v = 0.f;
  if (n < 324) v = Woff[(size_t)k * 324 + n];
  else if (n < 486) v = Wattn[(size_t)k * 162 + (n - 324)];
  Bt[i] = f2bf(v);
}

__global__ __launch_bounds__(64)
void biasoa_k(const float* __restrict__ boff, const float* __restrict__ battn,
              float* __restrict__ o) {
  int i = blockIdx.x * 64 + threadIdx.x;
  if (i < 512) o[i] = (i < 324) ? boff[i] : (i < 486 ? battn[i - 324] : 0.f);
}

// ------------- bf16 MFMA GEMM, 128x128 tile, FULL-K-chunk single-shot LDS ------------
// LDS: A [G groups][128 rows][4 slots x 16B] then B same at +G*8K. Chunk KC = G*32.
// Staged via global_load_lds with source-side octet swizzle u=(l&3)^((l>>3)&3);
// frag ds_read_b128 slot = kg ^ ((l15>>1)&3) -> 2-way bank aliasing (free).
// No mid-K barriers: one stage burst + one __syncthreads per chunk.
// MODE 0: fp32 C[M,N]. MODE 1: value permute -> bf16 (N,H,LIN,64).
template <int MODE, int G, int CH, int NBX, int NBY, int CPX>
__global__ __launch_bounds__(256)
void mfma_gemm_k(const ushort_t* __restrict__ A, const ushort_t* __restrict__ Bt,
                 const float* __restrict__ bias, void* __restrict__ Cout,
                 int N, int K) {
  __shared__ char lds[2 * G * 8192];
  const int bid = blockIdx.x;
  const int r = (bid & 7) * CPX + (bid >> 3);
  if (r >= NBX * NBY) return;
  const int bx = r / NBY, by = r - bx * NBY;
  const int m0 = bx * 128, n0 = by * 128;

  const int t = threadIdx.x;
  const int lane = t & 63, wid = t >> 6;
  const int wr = wid >> 1, wc = wid & 1;
  const int l15 = lane & 15, kg = lane >> 4;

  // staging geometry (lane-only swizzle): quad covers one row's 64B window
  const int srow = lane >> 2;                       // 0..15 within 16-row strip
  const int u = (lane & 3) ^ ((lane >> 3) & 3);     // source octet-in-quad
  const int rsw = (l15 >> 1) & 3;                   // reader slot xor

  f4v acc[4][4];
#pragma unroll
  for (int i = 0; i < 4; ++i)
#pragma unroll
    for (int j = 0; j < 4; ++j) acc[i][j] = (f4v){0.f, 0.f, 0.f, 0.f};

  for (int ch = 0; ch < CH; ++ch) {
    if (ch) __syncthreads();                        // prior chunk reads complete
    const int kb = ch * G * 32;
    // stage A and B full chunk: per thread 2*G insts each
#pragma unroll
    for (int g = 0; g < G; ++g) {
#pragma unroll
      for (int h = 0; h < 2; ++h) {
        const int R = h * 64 + wid * 16 + srow;
        const size_t ka = (size_t)(m0 + R) * K + kb + (g * 4 + u) * 8;
        const size_t kbb = (size_t)(n0 + R) * K + kb + (g * 4 + u) * 8;
        char* da = &lds[g * 8192 + h * 4096 + wid * 1024];
        char* db = &lds[G * 8192 + g * 8192 + h * 4096 + wid * 1024];
        gload16(A + ka, da);
        gload16(Bt + kbb, db);
      }
    }
    __syncthreads();                                // vmcnt(0) + barrier

    // compute: G k-steps of 16 MFMA, no syncs
#pragma unroll
    for (int ks = 0; ks < G; ++ks) {
      const char* la = &lds[ks * 8192];
      const char* lb = &lds[G * 8192 + ks * 8192];
      s8v av[4], bv[4];
#pragma unroll
      for (int mr = 0; mr < 4; ++mr) {
        const int R = wr * 64 + mr * 16 + l15;
        av[mr] = *(const s8v*)(la + R * 64 + ((kg ^ rsw) << 4));
      }
#pragma unroll
      for (int nr = 0; nr < 4; ++nr) {
        const int C = wc * 64 + nr * 16 + l15;
        bv[nr] = *(const s8v*)(lb + C * 64 + ((kg ^ rsw) << 4));
      }
#pragma unroll
      for (int mr = 0; mr < 4; ++mr)
#pragma unroll
        for (int nr = 0; nr < 4; ++nr)
          acc[mr][nr] = __builtin_amdgcn_mfma_f32_16x16x32_bf16(av[mr], bv[nr],
                                                                acc[mr][nr], 0, 0, 0);
    }
  }

  // epilogue: D frag col=lane&15, row=(lane>>4)*4+j
  if (MODE == 0) {
#pragma unroll
    for (int mr = 0; mr < 4; ++mr) {
#pragma unroll
      for (int nr = 0; nr < 4; ++nr) {
        const int col = n0 + wc * 64 + nr * 16 + l15;
        const float bs = bias[col];
#pragma unroll
        for (int j = 0; j < 4; ++j) {
          const int row = m0 + wr * 64 + mr * 16 + kg * 4 + j;
          ((float*)Cout)[(size_t)row * N + col] = acc[mr][nr][j] + bs;
        }
      }
    }
  } else {
    const int bq = bx / 129;                  // batch (scalar)
    const int rb = (bx - bq * 129) * 128;     // row base within batch
#pragma unroll
    for (int mr = 0; mr < 4; ++mr) {
#pragma unroll
      for (int nr = 0; nr < 4; ++nr) {
        const int col = n0 + wc * 64 + nr * 16 + l15;   // < 384
        const int h = col >> 6, dd = col & 63;
        const float bs = bias[col];
        ushort_t* base = (ushort_t*)Cout + (size_t)(bq * HH + h) * LIN * DH + dd;
#pragma unroll
        for (int j = 0; j < 4; ++j) {
          const int ii = rb + wr * 64 + mr * 16 + kg * 4 + j;
          if (ii < LIN) base[(size_t)ii * DH] = f2bf(acc[mr][nr][j] + bs);
        }
      }
    }
  }
}

// ---------------- fused softmax + bilinear sampling ----------------
__global__ __launch_bounds__(256)
void deform_sample_k(const ushort_t* __restrict__ value,   // bf16 (N,H,LIN,64)
                     const float* __restrict__ oa,         // (N*LQ, 512): off|logit
                     const float* __restrict__ refp,       // (N*LQ, 3, 2)
                     uint_t* __restrict__ otmp) {          // bf16 pairs (N*LQ, 192)
  __shared__ int4 sp[4][56];
  const int lane = threadIdx.x & 63, wv = threadIdx.x >> 6;
  const int wid = blockIdx.x * 4 + wv;
  const int s = wid >> 11;          // slice 0..23
  const int qq = wid & 2047;
  const int nb = s / HH, h = s - nb * HH;
  const int nq = nb * LQ + qq;

  float lg = -INFINITY;
  if (lane < 27) lg = oa[(size_t)nq * NOA + 324 + h * 27 + lane];
  float mx = lg;
#pragma unroll
  for (int m = 1; m < 64; m <<= 1) mx = fmaxf(mx, __shfl_xor(mx, m, 64));
  float e = (lane < 27) ? __expf(lg - mx) : 0.f;
  float ssum = e;
#pragma unroll
  for (int m = 1; m < 64; m <<= 1) ssum += __shfl_xor(ssum, m, 64);

  if (lane < 27) {
    const float aw = e / ssum;
    const int lvl = (lane >= 18) ? 2 : (lane >= 9 ? 1 : 0);
    const float Wf = (lvl == 0) ? 112.f : (lvl == 1 ? 56.f : 28.f);
    const int Wi = (lvl == 0) ? 112 : (lvl == 1 ? 56 : 28);
    const int base = (lvl == 0) ? 0 : (lvl == 1 ? 12544 : 15680);
    const float2 rp = *(const float2*)(refp + (size_t)nq * 6 + lvl * 2);
    const float2 of = *(const float2*)(oa + (size_t)nq * NOA + h * 54 + lane * 2);
    const float x = rp.x * Wf + of.x - 0.5f;
    const float y = rp.y * Wf + of.y - 0.5f;
    const float x0f = floorf(x), y0f = floorf(y);
    const float wx1 = x - x0f, wy1 = y - y0f;
    const float wx0 = 1.f - wx1, wy0 = 1.f - wy1;
    const int x0 = (int)x0f, y0 = (int)y0f;
    const int x1 = x0 + 1, y1 = y0 + 1;
    const bool bx0 = (x0 >= 0) & (x0 < Wi), bx1 = (x1 >= 0) & (x1 < Wi);
    const bool by0 = (y0 >= 0) & (y0 < Wi), by1 = (y1 >= 0) & (y1 < Wi);
    const int a00 = (bx0 & by0) ? ((base + y0 * Wi + x0) << 7) : 0;
    const int a01 = (bx1 & by0) ? ((base + y0 * Wi + x1) << 7) : 0;
    const int a10 = (bx0 & by1) ? ((base + y1 * Wi + x0) << 7) : 0;
    const int a11 = (bx1 & by1) ? ((base + y1 * Wi + x1) << 7) : 0;
    const float w00 = (bx0 & by0) ? aw * wx0 * wy0 : 0.f;
    const float w01 = (bx1 & by0) ? aw * wx1 * wy0 : 0.f;
    const float w10 = (bx0 & by1) ? aw * wx0 * wy1 : 0.f;
    const float w11 = (bx1 & by1) ? aw * wx1 * wy1 : 0.f;
    sp[wv][lane * 2 + 0] = make_int4(a00, __float_as_int(w00), a01, __float_as_int(w01));
    sp[wv][lane * 2 + 1] = make_int4(a10, __float_as_int(w10), a11, __float_as_int(w11));
  } else if (lane == 27) {
    sp[wv][54] = make_int4(0, 0, 0, 0);
    sp[wv][55] = make_int4(0, 0, 0, 0);
  }
  __syncthreads();

  const uint_t slice = (uint_t)__builtin_amdgcn_readfirstlane(s);
  const char* vbase = (const char*)value + (size_t)slice * (LIN * DH * 2);
  const int j4 = (lane & 31) * 4;
  const int half = lane >> 5;
  float a0 = 0.f, a1 = 0.f;
#pragma unroll 2
  for (int i = 0; i < 14; ++i) {
    const int pt = half * 14 + i;
    const int4 c01 = sp[wv][pt * 2];
    const int4 c23 = sp[wv][pt * 2 + 1];
    const uint_t u0 = *(const uint_t*)(vbase + (uint_t)(c01.x + j4));
    const uint_t u1 = *(const uint_t*)(vbase + (uint_t)(c01.z + j4));
    const uint_t u2 = *(const uint_t*)(vbase + (uint_t)(c23.x + j4));
    const uint_t u3 = *(const uint_t*)(vbase + (uint_t)(c23.z + j4));
    const float w0 = __int_as_float(c01.y), w1 = __int_as_float(c01.w);
    const float w2 = __int_as_float(c23.y), w3 = __int_as_float(c23.w);
    a0 += w0 * __uint_as_float(u0 << 16);
    a1 += w0 * __uint_as_float(u0 & 0xffff0000u);
    a0 += w1 * __uint_as_float(u1 << 16);
    a1 += w1 * __uint_as_float(u1 & 0xffff0000u);
    a0 += w2 * __uint_as_float(u2 << 16);
    a1 += w2 * __uint_as_float(u2 & 0xffff0000u);
    a0 += w3 * __uint_as_float(u3 << 16);
    a1 += w3 * __uint_as_float(u3 & 0xffff0000u);
  }
  a0 += __shfl_xor(a0, 32, 64);
  a1 += __shfl_xor(a1, 32, 64);
  if (lane < 32) {
    const uint_t packed = (uint_t)f2bf(a0) | ((uint_t)f2bf(a1) << 16);
    otmp[(size_t)nq * 192 + h * 32 + lane] = packed;
  }
}

// ---------------- launch ----------------
extern "C" void kernel_launch(void* const* d_in, const int* in_sizes, int n_in,
                              void* d_out, int out_size, void* d_ws, size_t ws_size,
                              hipStream_t stream) {
  const float* tgt   = (const float*)d_in[0];
  const float* src   = (const float*)d_in[1];
  const float* qpos  = (const float*)d_in[2];
  const float* refp  = (const float*)d_in[3];
  const float* W_off  = (const float*)d_in[7];
  const float* b_off  = (const float*)d_in[8];
  const float* W_attn = (const float*)d_in[9];
  const float* b_attn = (const float*)d_in[10];
  const float* W_val  = (const float*)d_in[11];
  const float* b_val  = (const float*)d_in[12];
  const float* W_out  = (const float*)d_in[13];
  const float* b_out  = (const float*)d_in[14];

  char* ws = (char*)d_ws;
  ushort_t* src_bf  = (ushort_t*)(ws);              // 33,816,576 B (padded)
  uint_t*   otmp    = (uint_t*)  (ws);              // alias: src_bf dead before sampler
  ushort_t* q_bf    = (ushort_t*)(ws + 33816576);   //  4,194,304
  ushort_t* val_bf  = (ushort_t*)(ws + 38010880);   // 50,577,408
  float*    oa      = (float*)   (ws + 88588288);   // 16,777,216
  ushort_t* bt_val  = (ushort_t*)(ws + 105365504);  //    196,608
  ushort_t* bt_oa   = (ushort_t*)(ws + 105562112);  //    262,144
  ushort_t* bt_out  = (ushort_t*)(ws + 105824256);  //    196,608
  float*    bias_oa = (float*)   (ws + 106020864);  //      2,048

  // conversions
  addq_k<<<2048, 256, 0, stream>>>((const float4*)tgt, (const float4*)qpos,
                                   (ushort4*)q_bf, 524288);
  conv_pad_k<<<dim3(4128, NB), 256, 0, stream>>>((const float4*)src, (ushort4*)src_bf);
  tconv_k<<<384, 256, 0, stream>>>(W_val, bt_val, 256, 384, 98304);
  tconv_oa_k<<<512, 256, 0, stream>>>(W_off, W_attn, bt_oa);
  tconv_k<<<384, 256, 0, stream>>>(W_out, bt_out, 384, 256, 98304);
  biasoa_k<<<8, 64, 0, stream>>>(b_off, b_attn, bias_oa);

  // value = src @ W_val + b_val -> bf16 permuted (N,H,LIN,64)
  // G=8 (full K=256 in one shot), 516x3 = 1548 tiles, grid padded to 1552
  mfma_gemm_k<1, 8, 1, 516, 3, 194><<<1552, 256, 0, stream>>>(
      src_bf, bt_val, b_val, val_bf, NVAL, DM);
  // [off | logit] = q @ [W_off|W_attn] + bias  (fp32, N=512): 64x4 = 256 tiles
  mfma_gemm_k<0, 8, 1, 64, 4, 32><<<256, 256, 0, stream>>>(
      q_bf, bt_oa, bias_oa, oa, NOA, DM);

  // fused softmax + sampling -> otmp bf16 (aliases src_bf region)
  deform_sample_k<<<12288, 256, 0, stream>>>(val_bf, oa, refp, otmp);

  // out = otmp @ W_out + b_out (fp32, final, K=384): G=6, 2 chunks, 64x2 = 128 tiles
  mfma_gemm_k<0, 6, 2, 64, 2, 16><<<128, 256, 0, stream>>>(
      (const ushort_t*)otmp, bt_out, b_out, (float*)d_out, DM, NVAL);
}

// Round 7
// 118.754 us; speedup vs baseline: 1.2543x; 1.2543x over previous
//
#include <hip/hip_runtime.h>
#include <math.h>

#define NB 4
#define LQ 2048
#define DM 256
#define HH 6
#define DH 64
#define LIN 16464
#define LINP 16512          // padded rows per batch (129 * 128)
#define NOA 512             // fused off(324)+attn(162) padded
#define NVAL 384

typedef unsigned short ushort_t;
typedef unsigned int uint_t;
typedef __attribute__((ext_vector_type(8))) short s8v;   // 8 bf16 = 4 VGPR
typedef __attribute__((ext_vector_type(4))) float f4v;   // MFMA accumulator

__device__ __forceinline__ ushort_t f2bf(float f) {
  union { float f; unsigned u; } v; v.f = f;
  unsigned r = v.u + 0x7fffu + ((v.u >> 16) & 1u);  // RNE
  return (ushort_t)(r >> 16);
}

typedef __attribute__((address_space(3))) char lds_char_t;
typedef const __attribute__((address_space(1))) char glb_char_t;
__device__ __forceinline__ void gload16(const void* g, void* l) {
  __builtin_amdgcn_global_load_lds((glb_char_t*)g, (lds_char_t*)l, 16, 0, 0);
}

// ---------------- fused prep: addq + src conv/pad + all weight transposes + bias ----------------
__global__ __launch_bounds__(256)
void prep_k(const float4* __restrict__ tgt, const float4* __restrict__ qpos,
            ushort4* __restrict__ q_bf,
            const float4* __restrict__ src, ushort4* __restrict__ src_bf,
            const float* __restrict__ W_val, ushort_t* __restrict__ bt_val,
            const float* __restrict__ W_off, const float* __restrict__ W_attn,
            ushort_t* __restrict__ bt_oa,
            const float* __restrict__ W_out, ushort_t* __restrict__ bt_out,
            const float* __restrict__ b_off, const float* __restrict__ b_attn,
            float* __restrict__ bias_oa) {
  const int blk = blockIdx.x, tid = threadIdx.x;
  if (blk < 2048) {
    // q = bf16(tgt + query_pos), 524288 quads
    const int i = blk * 256 + tid;
    float4 x = tgt[i], y = qpos[i];
    ushort4 r;
    r.x = f2bf(x.x + y.x); r.y = f2bf(x.y + y.y);
    r.z = f2bf(x.z + y.z); r.w = f2bf(x.w + y.w);
    q_bf[i] = r;
  } else if (blk < 18560) {
    // src fp32 -> bf16, padded to LINP rows per batch
    const int ib = blk - 2048;
    const int b = ib / 4128;
    const int idx = (ib - b * 4128) * 256 + tid;
    const int r = idx >> 6, kq = idx & 63;
    ushort4 o;
    if (r < LIN) {
      float4 x = src[(size_t)(b * LIN + r) * 64 + kq];
      o.x = f2bf(x.x); o.y = f2bf(x.y); o.z = f2bf(x.z); o.w = f2bf(x.w);
    } else {
      o.x = o.y = o.z = o.w = 0;
    }
    src_bf[(size_t)(b * LINP + r) * 64 + kq] = o;
  } else {
    const int i = (blk - 18560) * 256 + tid;
    if (i < 98304) {              // bt_val[n][k] = W_val[k][n], 384x256
      const int n = i >> 8, k = i & 255;
      bt_val[i] = f2bf(W_val[(size_t)k * 384 + n]);
    } else if (i < 229376) {      // bt_oa: 512x256, rows 0..323 off, 324..485 attn
      const int j = i - 98304;
      const int n = j >> 8, k = j & 255;
      float v = 0.f;
      if (n < 324) v = W_off[(size_t)k * 324 + n];
      else if (n < 486) v = W_attn[(size_t)k * 162 + (n - 324)];
      bt_oa[j] = f2bf(v);
    } else if (i < 327680) {      // bt_out: 256x384
      const int j = i - 229376;
      const int n = j / 384, k = j - n * 384;
      bt_out[j] = f2bf(W_out[(size_t)k * 256 + n]);
    } else {                      // bias_oa 512
      const int j = i - 327680;
      if (j < 512) bias_oa[j] = (j < 324) ? b_off[j] : (j < 486 ? b_attn[j - 324] : 0.f);
    }
  }
}

// ------------- bf16 MFMA GEMM, swapped operands: D-row = output channel -------------
// 128(acts) x 128(channels) tile, BK=32, 3-buf counted-vmcnt pipeline (R5 structure).
// A-operand = weight rows (channels), B-operand = activation rows. Per (mr,nr) a lane
// holds 4 CONSECUTIVE channels -> 8B/16B vector stores (4x fewer store insts).
// LDS per buf: W-half [row][4 slots x 16B] at [0,8K), Act-half at [8K,16K);
// source octet swizzle u=(l&3)^((l>>3)&3), reader slot kg^((l15>>1)&3): 2-way free.
// Grid: 1-D bijective XCD chunking, channel-tile (y) fastest for act-tile L2 reuse.
// MODE 0: fp32 C[acts, channels] row-major. MODE 1: value permute -> bf16 (N,H,LIN,64).
template <int MODE, int NBX, int NBY, int CPX>
__global__ __launch_bounds__(256)
void mfma_gemm_k(const ushort_t* __restrict__ Act, const ushort_t* __restrict__ Wt,
                 const float* __restrict__ bias, void* __restrict__ Cout,
                 int N, int K) {
  __shared__ char lds[3][16384];
  const int bid = blockIdx.x;
  const int r = (bid & 7) * CPX + (bid >> 3);
  if (r >= NBX * NBY) return;
  const int bx = r / NBY, by = r - bx * NBY;
  const int m0 = bx * 128, n0 = by * 128;   // m0: act rows, n0: channels

  const int t = threadIdx.x;
  const int lane = t & 63, wid = t >> 6;
  const int wr = wid >> 1, wc = wid & 1;
  const int l15 = lane & 15, kg = lane >> 4;
  const int nk = K >> 5;

  const int srow = lane >> 2;
  const int koct = (lane & 3) ^ ((lane >> 3) & 3);
  const int rsw = (l15 >> 1) & 3;

  const size_t WA0 = (size_t)(n0 + wid * 16 + srow) * K + koct * 8;
  const size_t WA1 = WA0 + (size_t)64 * K;
  const size_t XB0 = (size_t)(m0 + wid * 16 + srow) * K + koct * 8;
  const size_t XB1 = XB0 + (size_t)64 * K;

  f4v acc[4][4];
#pragma unroll
  for (int i = 0; i < 4; ++i)
#pragma unroll
    for (int j = 0; j < 4; ++j) acc[i][j] = (f4v){0.f, 0.f, 0.f, 0.f};

#define STAGE(ks_)                                                       \
  { char* d_ = &lds[(ks_) % 3][0]; const int ko_ = (ks_) << 5;           \
    gload16(Wt + WA0 + ko_,  d_ + wid * 1024);                           \
    gload16(Wt + WA1 + ko_,  d_ + 4096 + wid * 1024);                    \
    gload16(Act + XB0 + ko_, d_ + 8192 + wid * 1024);                    \
    gload16(Act + XB1 + ko_, d_ + 12288 + wid * 1024); }

  STAGE(0);
  STAGE(1);

  for (int ks = 0; ks < nk; ++ks) {
    if (ks + 1 < nk) {
      asm volatile("s_waitcnt vmcnt(4)" ::: "memory");
    } else {
      asm volatile("s_waitcnt vmcnt(0)" ::: "memory");
    }
    __builtin_amdgcn_s_barrier();
    asm volatile("" ::: "memory");
    if (ks + 2 < nk) STAGE(ks + 2);

    const char* d = &lds[ks % 3][0];
    s8v av[4], bv[4];
#pragma unroll
    for (int mr = 0; mr < 4; ++mr)   // weight rows (channels)
      av[mr] = *(const s8v*)(d + (wr * 64 + mr * 16 + l15) * 64 + ((kg ^ rsw) << 4));
#pragma unroll
    for (int nr = 0; nr < 4; ++nr)   // activation rows
      bv[nr] = *(const s8v*)(d + 8192 + (wc * 64 + nr * 16 + l15) * 64 + ((kg ^ rsw) << 4));
#pragma unroll
    for (int mr = 0; mr < 4; ++mr)
#pragma unroll
      for (int nr = 0; nr < 4; ++nr)
        acc[mr][nr] = __builtin_amdgcn_mfma_f32_16x16x32_bf16(av[mr], bv[nr],
                                                              acc[mr][nr], 0, 0, 0);
  }
#undef STAGE

  // epilogue: D row = channel = n0+wr*64+mr*16+kg*4+j (j contiguous!), col = act row
  if (MODE == 0) {
#pragma unroll
    for (int mr = 0; mr < 4; ++mr) {
      const int ch = n0 + wr * 64 + mr * 16 + kg * 4;
      const float4 b4 = *(const float4*)(bias + ch);
#pragma unroll
      for (int nr = 0; nr < 4; ++nr) {
        const int qrow = m0 + wc * 64 + nr * 16 + l15;
        float4 v;
        v.x = acc[mr][nr][0] + b4.x;
        v.y = acc[mr][nr][1] + b4.y;
        v.z = acc[mr][nr][2] + b4.z;
        v.w = acc[mr][nr][3] + b4.w;
        *(float4*)((float*)Cout + (size_t)qrow * N + ch) = v;
      }
    }
  } else {
    const int bq = bx / 129;
    const int rb = (bx - bq * 129) * 128;
#pragma unroll
    for (int mr = 0; mr < 4; ++mr) {
      const int ch = n0 + wr * 64 + mr * 16 + kg * 4;   // < 384
      const int h = ch >> 6, dd = ch & 63;
      const float4 b4 = *(const float4*)(bias + ch);
      ushort_t* obase = (ushort_t*)Cout + (size_t)(bq * HH + h) * LIN * DH + dd;
#pragma unroll
      for (int nr = 0; nr < 4; ++nr) {
        const int ii = rb + wc * 64 + nr * 16 + l15;
        if (ii < LIN) {
          ushort4 o;
          o.x = f2bf(acc[mr][nr][0] + b4.x);
          o.y = f2bf(acc[mr][nr][1] + b4.y);
          o.z = f2bf(acc[mr][nr][2] + b4.z);
          o.w = f2bf(acc[mr][nr][3] + b4.w);
          *(ushort4*)(obase + (size_t)ii * DH) = o;
        }
      }
    }
  }
}

// ---------------- fused softmax + bilinear sampling ----------------
__global__ __launch_bounds__(256)
void deform_sample_k(const ushort_t* __restrict__ value,   // bf16 (N,H,LIN,64)
                     const float* __restrict__ oa,         // (N*LQ, 512): off|logit
                     const float* __restrict__ refp,       // (N*LQ, 3, 2)
                     uint_t* __restrict__ otmp) {          // bf16 pairs (N*LQ, 192)
  __shared__ int4 sp[4][56];
  const int lane = threadIdx.x & 63, wv = threadIdx.x >> 6;
  const int wid = blockIdx.x * 4 + wv;
  const int s = wid >> 11;          // slice 0..23
  const int qq = wid & 2047;
  const int nb = s / HH, h = s - nb * HH;
  const int nq = nb * LQ + qq;

  float lg = -INFINITY;
  if (lane < 27) lg = oa[(size_t)nq * NOA + 324 + h * 27 + lane];
  float mx = lg;
#pragma unroll
  for (int m = 1; m < 64; m <<= 1) mx = fmaxf(mx, __shfl_xor(mx, m, 64));
  float e = (lane < 27) ? __expf(lg - mx) : 0.f;
  float ssum = e;
#pragma unroll
  for (int m = 1; m < 64; m <<= 1) ssum += __shfl_xor(ssum, m, 64);

  if (lane < 27) {
    const float aw = e / ssum;
    const int lvl = (lane >= 18) ? 2 : (lane >= 9 ? 1 : 0);
    const float Wf = (lvl == 0) ? 112.f : (lvl == 1 ? 56.f : 28.f);
    const int Wi = (lvl == 0) ? 112 : (lvl == 1 ? 56 : 28);
    const int base = (lvl == 0) ? 0 : (lvl == 1 ? 12544 : 15680);
    const float2 rp = *(const float2*)(refp + (size_t)nq * 6 + lvl * 2);
    const float2 of = *(const float2*)(oa + (size_t)nq * NOA + h * 54 + lane * 2);
    const float x = rp.x * Wf + of.x - 0.5f;
    const float y = rp.y * Wf + of.y - 0.5f;
    const float x0f = floorf(x), y0f = floorf(y);
    const float wx1 = x - x0f, wy1 = y - y0f;
    const float wx0 = 1.f - wx1, wy0 = 1.f - wy1;
    const int x0 = (int)x0f, y0 = (int)y0f;
    const int x1 = x0 + 1, y1 = y0 + 1;
    const bool bx0 = (x0 >= 0) & (x0 < Wi), bx1 = (x1 >= 0) & (x1 < Wi);
    const bool by0 = (y0 >= 0) & (y0 < Wi), by1 = (y1 >= 0) & (y1 < Wi);
    const int a00 = (bx0 & by0) ? ((base + y0 * Wi + x0) << 7) : 0;
    const int a01 = (bx1 & by0) ? ((base + y0 * Wi + x1) << 7) : 0;
    const int a10 = (bx0 & by1) ? ((base + y1 * Wi + x0) << 7) : 0;
    const int a11 = (bx1 & by1) ? ((base + y1 * Wi + x1) << 7) : 0;
    const float w00 = (bx0 & by0) ? aw * wx0 * wy0 : 0.f;
    const float w01 = (bx1 & by0) ? aw * wx1 * wy0 : 0.f;
    const float w10 = (bx0 & by1) ? aw * wx0 * wy1 : 0.f;
    const float w11 = (bx1 & by1) ? aw * wx1 * wy1 : 0.f;
    sp[wv][lane * 2 + 0] = make_int4(a00, __float_as_int(w00), a01, __float_as_int(w01));
    sp[wv][lane * 2 + 1] = make_int4(a10, __float_as_int(w10), a11, __float_as_int(w11));
  } else if (lane == 27) {
    sp[wv][54] = make_int4(0, 0, 0, 0);
    sp[wv][55] = make_int4(0, 0, 0, 0);
  }
  __syncthreads();

  const uint_t slice = (uint_t)__builtin_amdgcn_readfirstlane(s);
  const char* vbase = (const char*)value + (size_t)slice * (LIN * DH * 2);
  const int j4 = (lane & 31) * 4;
  const int half = lane >> 5;
  float a0 = 0.f, a1 = 0.f;
#pragma unroll 2
  for (int i = 0; i < 14; ++i) {
    const int pt = half * 14 + i;
    const int4 c01 = sp[wv][pt * 2];
    const int4 c23 = sp[wv][pt * 2 + 1];
    const uint_t u0 = *(const uint_t*)(vbase + (uint_t)(c01.x + j4));
    const uint_t u1 = *(const uint_t*)(vbase + (uint_t)(c01.z + j4));
    const uint_t u2 = *(const uint_t*)(vbase + (uint_t)(c23.x + j4));
    const uint_t u3 = *(const uint_t*)(vbase + (uint_t)(c23.z + j4));
    const float w0 = __int_as_float(c01.y), w1 = __int_as_float(c01.w);
    const float w2 = __int_as_float(c23.y), w3 = __int_as_float(c23.w);
    a0 += w0 * __uint_as_float(u0 << 16);
    a1 += w0 * __uint_as_float(u0 & 0xffff0000u);
    a0 += w1 * __uint_as_float(u1 << 16);
    a1 += w1 * __uint_as_float(u1 & 0xffff0000u);
    a0 += w2 * __uint_as_float(u2 << 16);
    a1 += w2 * __uint_as_float(u2 & 0xffff0000u);
    a0 += w3 * __uint_as_float(u3 << 16);
    a1 += w3 * __uint_as_float(u3 & 0xffff0000u);
  }
  a0 += __shfl_xor(a0, 32, 64);
  a1 += __shfl_xor(a1, 32, 64);
  if (lane < 32) {
    const uint_t packed = (uint_t)f2bf(a0) | ((uint_t)f2bf(a1) << 16);
    otmp[(size_t)nq * 192 + h * 32 + lane] = packed;
  }
}

// ---------------- launch ----------------
extern "C" void kernel_launch(void* const* d_in, const int* in_sizes, int n_in,
                              void* d_out, int out_size, void* d_ws, size_t ws_size,
                              hipStream_t stream) {
  const float* tgt   = (const float*)d_in[0];
  const float* src   = (const float*)d_in[1];
  const float* qpos  = (const float*)d_in[2];
  const float* refp  = (const float*)d_in[3];
  const float* W_off  = (const float*)d_in[7];
  const float* b_off  = (const float*)d_in[8];
  const float* W_attn = (const float*)d_in[9];
  const float* b_attn = (const float*)d_in[10];
  const float* W_val  = (const float*)d_in[11];
  const float* b_val  = (const float*)d_in[12];
  const float* W_out  = (const float*)d_in[13];
  const float* b_out  = (const float*)d_in[14];

  char* ws = (char*)d_ws;
  ushort_t* src_bf  = (ushort_t*)(ws);              // 33,816,576 B (padded)
  uint_t*   otmp    = (uint_t*)  (ws);              // alias: src_bf dead before sampler
  ushort_t* q_bf    = (ushort_t*)(ws + 33816576);   //  4,194,304
  ushort_t* val_bf  = (ushort_t*)(ws + 38010880);   // 50,577,408
  float*    oa      = (float*)   (ws + 88588288);   // 16,777,216
  ushort_t* bt_val  = (ushort_t*)(ws + 105365504);  //    196,608
  ushort_t* bt_oa   = (ushort_t*)(ws + 105562112);  //    262,144
  ushort_t* bt_out  = (ushort_t*)(ws + 105824256);  //    196,608
  float*    bias_oa = (float*)   (ws + 106020864);  //      2,048

  // fused prep: q add+cvt, src cvt+pad, weight transposes, bias concat
  prep_k<<<19842, 256, 0, stream>>>((const float4*)tgt, (const float4*)qpos,
                                    (ushort4*)q_bf, (const float4*)src,
                                    (ushort4*)src_bf, W_val, bt_val,
                                    W_off, W_attn, bt_oa, W_out, bt_out,
                                    b_off, b_attn, bias_oa);

  // value = src @ W_val + b_val -> bf16 permuted (N,H,LIN,64); 516x3 tiles
  mfma_gemm_k<1, 516, 3, 194><<<1552, 256, 0, stream>>>(
      src_bf, bt_val, b_val, val_bf, NVAL, DM);
  // [off | logit] = q @ [W_off|W_attn] + bias (fp32, N=512): 64x4 tiles
  mfma_gemm_k<0, 64, 4, 32><<<256, 256, 0, stream>>>(
      q_bf, bt_oa, bias_oa, oa, NOA, DM);

  // fused softmax + sampling -> otmp bf16 (aliases src_bf region)
  deform_sample_k<<<12288, 256, 0, stream>>>(val_bf, oa, refp, otmp);

  // out = otmp @ W_out + b_out (fp32, final, K=384): 64x2 tiles
  mfma_gemm_k<0, 64, 2, 16><<<128, 256, 0, stream>>>(
      (const ushort_t*)otmp, bt_out, b_out, (float*)d_out, DM, NVAL);
}